// Round 16
// baseline (691.068 us; speedup 1.0000x reference)
//
#include <hip/hip_runtime.h>
#include <cmath>

// DGCNN: B=8, N=2048, k=20, dims 3->64->128->256, fp32 throughout.
static constexpr int Bb  = 8;
static constexpr int Nn  = 2048;
static constexpr int KNB = 20;
static constexpr int NPT = Bb * Nn;
static constexpr int NTRI = 528;    // 32*33/2 triangular 64-tiles per batch
#define EPSBN 1e-5f

// LDS column swizzle for 128-wide staging (gemmAB).
__device__ __forceinline__ int permc(int c) { return c ^ (4 * (c >> 5)); }

// monotone uint key: order(key) == order(float); finite inputs -> key > 0
__device__ __forceinline__ unsigned mkkey(float v) {
  unsigned u = __float_as_uint(v);
  return (u & 0x80000000u) ? ~u : (u | 0x80000000u);
}

// ---------------------------------------------------------------- row |x|^2
__global__ __launch_bounds__(256) void row_sumsq_k(const float* __restrict__ f,
                                                   float* __restrict__ xx, int C) {
  int g = blockIdx.x * 256 + threadIdx.x;
  if (g >= NPT) return;
  const float* r = f + (size_t)g * C;
  float s = 0.f;
  if ((C & 3) == 0) {
    const float4* r4 = (const float4*)r;
    for (int j = 0; j < C / 4; ++j) {
      float4 v = r4[j];
      s += v.x * v.x + v.y * v.y + v.z * v.z + v.w * v.w;
    }
  } else {
    for (int j = 0; j < C; ++j) { float v = r[j]; s += v * v; }
  }
  xx[g] = s;
}

// ------------------------------------------------- neg_dist, UPPER-TRI 64x64
// nd[n][m] = 2*x_n.x_m - |x_n|^2 - |x_m|^2 ; diag forced to exactly 0.
// R16: write ONLY the 528 upper-triangular tiles per batch (67 MB, not 131).
// R8..R15 evidence: dist converged on 131 MB @ ~1.35 TB/s across every
// config — HBM write-stream ceiling. The mirror is never materialized;
// topk reads the transposed element for cols below the diagonal tile.
// Mirror epilogue + LDS transpose deleted. XCD swizzle kept (batch =
// blockIdx.x & 7) so the per-batch slab stays in one XCD's L2 (topk's
// strided mirror reads are L2-amortized across the 64 rows of a tile-row).
// HARD-LEARNED (R6/R7): no launch_bounds min-waves (spill); no runtime-
// indexed register arrays (scratch demotion). (R9/R10): no serial
// single-lane LDS selection / divergent long loops. (R12/R14): all-distinct
// b128 wave accesses are full-BW floor, not conflicts.
__global__ __launch_bounds__(256) void dist_k(const float* __restrict__ f,
                                              const float* __restrict__ xx,
                                              float* __restrict__ nd, int C) {
  __shared__ float As[16 * 68];     // [k][row] 64 rows
  __shared__ float Bs[16 * 68];     // [k][col] 64 cols
  int tid = threadIdx.x, tx = tid & 15, ty = tid >> 4;
  int b, p;
  if (gridDim.x == NTRI * Bb) { b = blockIdx.x & 7; p = blockIdx.x >> 3; }
  else                        { b = blockIdx.z;     p = blockIdx.x; }
  const float* fb  = f  + (size_t)b * Nn * C;
  const float* xxb = xx + (size_t)b * Nn;
  float* ndb = nd + (size_t)b * Nn * Nn;
  // triangular decode: p in [0,528) -> (rblk, cblk), rblk <= cblk
  int rblk = 0;
  while (p >= 32 - rblk) { p -= 32 - rblk; ++rblk; }
  int rb = rblk * 64, cb = (rblk + p) * 64;
  int kk0 = tid & 15, rr = tid >> 4;
  float acc[4][4] = {};
  float pa[4], pb[4];
  {
    bool ok = kk0 < C;
    #pragma unroll
    for (int t = 0; t < 4; ++t) {
      int r2 = rr + 16 * t;
      pa[t] = ok ? fb[(size_t)(rb + r2) * C + kk0] : 0.f;
      pb[t] = ok ? fb[(size_t)(cb + r2) * C + kk0] : 0.f;
    }
  }
  for (int k0 = 0; k0 < C; k0 += 16) {
    __syncthreads();
    #pragma unroll
    for (int t = 0; t < 4; ++t) {
      int r2 = rr + 16 * t;
      As[kk0 * 68 + r2] = pa[t];
      Bs[kk0 * 68 + r2] = pb[t];
    }
    __syncthreads();
    if (k0 + 16 < C) {
      int k2 = k0 + 16 + kk0;
      bool ok2 = k2 < C;
      #pragma unroll
      for (int t = 0; t < 4; ++t) {
        int r2 = rr + 16 * t;
        pa[t] = ok2 ? fb[(size_t)(rb + r2) * C + k2] : 0.f;
        pb[t] = ok2 ? fb[(size_t)(cb + r2) * C + k2] : 0.f;
      }
    }
    #pragma unroll
    for (int kk = 0; kk < 16; ++kk) {
      float4 a4 = *(const float4*)&As[kk * 68 + 4 * ty];   // broadcast x16
      float4 b4 = *(const float4*)&Bs[kk * 68 + 4 * tx];   // 16 distinct
      float av[4] = {a4.x, a4.y, a4.z, a4.w};
      float bv[4] = {b4.x, b4.y, b4.z, b4.w};
      #pragma unroll
      for (int i = 0; i < 4; ++i)
        #pragma unroll
        for (int j = 0; j < 4; ++j) acc[i][j] += av[i] * bv[j];
    }
  }
  // epilogue: finalize + store this tile only (no mirror)
  float xr[4], xc[4];
  #pragma unroll
  for (int i = 0; i < 4; ++i) xr[i] = xxb[rb + 4 * ty + i];
  #pragma unroll
  for (int j = 0; j < 4; ++j) xc[j] = xxb[cb + 4 * tx + j];
  #pragma unroll
  for (int i = 0; i < 4; ++i) {
    int grow = rb + 4 * ty + i;
    #pragma unroll
    for (int j = 0; j < 4; ++j) {
      int gcol = cb + 4 * tx + j;
      float v = 2.f * acc[i][j] - xr[i] - xc[j];
      acc[i][j] = (grow == gcol) ? 0.f : v;
    }
    *(float4*)&ndb[(size_t)grow * Nn + cb + 4 * tx] =
        make_float4(acc[i][0], acc[i][1], acc[i][2], acc[i][3]);
  }
}

// ------------------------------------------------- top-20: threshold select
// One block per row. Upper-triangle-only nd (R16): row rn, tile r0 = rn>>6.
// Cols m >= 64*r0: direct nd[rn][m] (vectorized). Cols m < 64*r0: transposed
// element nd[m][rn] (8 KB-strided scalars; L2-amortized — the 64 rows of a
// tile-row jointly consume each fetched line, same XCD via batch swizzle).
// Selection: (1) 8 keys/thread in REGISTERS (cols 8*tid..8*tid+7), per-
// thread max; (2) each wave extracts the 5th-largest of its 64 maxima
// (shuffle-only); (3) T = min over 4 waves => >=20 values >= T in row =>
// true top-20 + boundary ties are in {key >= T}; (4) append candidates;
// (5) parallel rank-count extraction (R14). Lex order matches lax.top_k.
__global__ __launch_bounds__(256) void topk_k(const float* __restrict__ nd,
                                              int* __restrict__ outidx) {
  __shared__ unsigned ck[Nn];
  __shared__ unsigned short ci[Nn];
  __shared__ unsigned Tw[4];
  __shared__ int s_cnt;
  int tid = threadIdx.x, lane = tid & 63;
  int n;
  if (gridDim.x == NPT) {            // XCD swizzle matches dist_k's writes
    int bb = blockIdx.x & 7, row = blockIdx.x >> 3;
    n = bb * Nn + row;
  } else {
    n = blockIdx.x;
  }
  int rn = n & (Nn - 1);             // row within batch
  size_t rowBase   = (size_t)n * Nn; // direct row start (global layout)
  size_t batchBase = (size_t)(n - rn) * Nn;
  int dStart = (rn >> 6) << 6;       // first directly-stored col
  int* orow = outidx + (size_t)n * KNB;
  if (tid == 0) s_cnt = 0;
  int mStart = 8 * tid;              // this thread's 8 cols (never straddles)
  unsigned k0, k1, k2, k3, k4, k5, k6, k7;
  if (mStart >= dStart) {
    const float4* dp = (const float4*)(nd + rowBase + mStart);
    float4 va = dp[0], vb = dp[1];
    k0 = mkkey(va.x); k1 = mkkey(va.y); k2 = mkkey(va.z); k3 = mkkey(va.w);
    k4 = mkkey(vb.x); k5 = mkkey(vb.y); k6 = mkkey(vb.z); k7 = mkkey(vb.w);
  } else {
    const float* mp = nd + batchBase + (size_t)mStart * Nn + rn;
    k0 = mkkey(mp[0]);        k1 = mkkey(mp[(size_t)Nn]);
    k2 = mkkey(mp[2 * (size_t)Nn]); k3 = mkkey(mp[3 * (size_t)Nn]);
    k4 = mkkey(mp[4 * (size_t)Nn]); k5 = mkkey(mp[5 * (size_t)Nn]);
    k6 = mkkey(mp[6 * (size_t)Nn]); k7 = mkkey(mp[7 * (size_t)Nn]);
  }
  unsigned t1 = k0;
  t1 = k1 > t1 ? k1 : t1; t1 = k2 > t1 ? k2 : t1; t1 = k3 > t1 ? k3 : t1;
  t1 = k4 > t1 ? k4 : t1; t1 = k5 > t1 ? k5 : t1; t1 = k6 > t1 ? k6 : t1;
  t1 = k7 > t1 ? k7 : t1;
  bool alive = true;
  unsigned wmax = 0;
  #pragma unroll
  for (int r = 0; r < 5; ++r) {
    unsigned v = alive ? t1 : 0u;
    wmax = v;
    #pragma unroll
    for (int off = 1; off < 64; off <<= 1) {
      unsigned o = (unsigned)__shfl_xor((int)wmax, off, 64);
      wmax = o > wmax ? o : wmax;
    }
    unsigned long long ball = __ballot(alive && t1 == wmax);
    int first = __ffsll((long long)ball) - 1;
    if (lane == first) alive = false;
  }
  if (lane == 0) Tw[tid >> 6] = wmax;
  __syncthreads();
  unsigned T = Tw[0];
  T = Tw[1] < T ? Tw[1] : T;
  T = Tw[2] < T ? Tw[2] : T;
  T = Tw[3] < T ? Tw[3] : T;
  if (k0 >= T) { int p2 = atomicAdd(&s_cnt, 1); ck[p2] = k0; ci[p2] = (unsigned short)(mStart); }
  if (k1 >= T) { int p2 = atomicAdd(&s_cnt, 1); ck[p2] = k1; ci[p2] = (unsigned short)(mStart + 1); }
  if (k2 >= T) { int p2 = atomicAdd(&s_cnt, 1); ck[p2] = k2; ci[p2] = (unsigned short)(mStart + 2); }
  if (k3 >= T) { int p2 = atomicAdd(&s_cnt, 1); ck[p2] = k3; ci[p2] = (unsigned short)(mStart + 3); }
  if (k4 >= T) { int p2 = atomicAdd(&s_cnt, 1); ck[p2] = k4; ci[p2] = (unsigned short)(mStart + 4); }
  if (k5 >= T) { int p2 = atomicAdd(&s_cnt, 1); ck[p2] = k5; ci[p2] = (unsigned short)(mStart + 5); }
  if (k6 >= T) { int p2 = atomicAdd(&s_cnt, 1); ck[p2] = k6; ci[p2] = (unsigned short)(mStart + 6); }
  if (k7 >= T) { int p2 = atomicAdd(&s_cnt, 1); ck[p2] = k7; ci[p2] = (unsigned short)(mStart + 7); }
  __syncthreads();
  int nc = s_cnt;
  for (int j = tid; j < nc; j += 256) {
    unsigned kj = ck[j];
    unsigned ij = ci[j];
    int rank = 0;
    for (int i = 0; i < nc; ++i) {
      unsigned ki = ck[i];             // broadcast read
      unsigned ii = ci[i];
      rank += (ki > kj || (ki == kj && ii < ij)) ? 1 : 0;
    }
    if (rank < KNB) orow[rank] = (int)ij;
  }
}

// ------------------------------------------------- fused GEMM: A = X*W1^T + b, Bv = X*W2^T
__global__ __launch_bounds__(256) void gemmAB_k(const float* __restrict__ X,
                                                const float* __restrict__ W,
                                                const float* __restrict__ bias,
                                                float* __restrict__ A,
                                                float* __restrict__ Bv,
                                                int COUT, int CIN) {
  __shared__ float Xs[16][132];
  __shared__ float Ws[16][132];
  int tid = threadIdx.x, tx = tid & 15, ty = tid >> 4;
  int mb = blockIdx.y * 128, cb = blockIdx.x * 128;
  int kk0 = tid & 15, rr = tid >> 4;
  int ldw = 2 * CIN;
  float acc[8][8] = {};
  for (int k0 = 0; k0 < CIN; k0 += 16) {
    int k = k0 + kk0;
    bool ok = k < CIN;
    #pragma unroll
    for (int r2 = rr; r2 < 128; r2 += 16) {
      Xs[kk0][permc(r2)] = ok ? X[(size_t)(mb + r2) * CIN + k] : 0.f;
      int c2 = cb + r2;
      const float* wr = (c2 < COUT) ? (W + (size_t)c2 * ldw)
                                    : (W + (size_t)(c2 - COUT) * ldw + CIN);
      Ws[kk0][permc(r2)] = ok ? wr[k] : 0.f;
    }
    __syncthreads();
    #pragma unroll
    for (int kk = 0; kk < 16; ++kk) {
      float4 a0 = *(const float4*)&Xs[kk][permc(8 * ty)];
      float4 a1 = *(const float4*)&Xs[kk][permc(8 * ty + 4)];
      float4 b0 = *(const float4*)&Ws[kk][permc(8 * tx)];
      float4 b1 = *(const float4*)&Ws[kk][permc(8 * tx + 4)];
      float av[8] = {a0.x, a0.y, a0.z, a0.w, a1.x, a1.y, a1.z, a1.w};
      float bv[8] = {b0.x, b0.y, b0.z, b0.w, b1.x, b1.y, b1.z, b1.w};
      #pragma unroll
      for (int i = 0; i < 8; ++i)
        #pragma unroll
        for (int j = 0; j < 8; ++j) acc[i][j] += av[i] * bv[j];
    }
    __syncthreads();
  }
  int c0 = cb + 8 * tx;
  bool isA = (c0 < COUT);
  float bb[8] = {0, 0, 0, 0, 0, 0, 0, 0};
  if (isA) {
    float4 b4a = *(const float4*)&bias[c0];
    float4 b4b = *(const float4*)&bias[c0 + 4];
    bb[0] = b4a.x; bb[1] = b4a.y; bb[2] = b4a.z; bb[3] = b4a.w;
    bb[4] = b4b.x; bb[5] = b4b.y; bb[6] = b4b.z; bb[7] = b4b.w;
  }
  float* dst = isA ? A : Bv;
  int cc = isA ? c0 : (c0 - COUT);
  #pragma unroll
  for (int i = 0; i < 8; ++i) {
    int m = mb + 8 * ty + i;
    *(float4*)&dst[(size_t)m * COUT + cc] =
        make_float4(acc[i][0] + bb[0], acc[i][1] + bb[1], acc[i][2] + bb[2], acc[i][3] + bb[3]);
    *(float4*)&dst[(size_t)m * COUT + cc + 4] =
        make_float4(acc[i][4] + bb[4], acc[i][5] + bb[5], acc[i][6] + bb[6], acc[i][7] + bb[7]);
  }
}

// ------------------------------------------------- gather-combine + stats
// XCD-aware: batch = blockIdx.x % 8 so each XCD's L2 caches one batch's Bv slice.
template <int COUT>
__global__ __launch_bounds__(256) void combine_k(const float* __restrict__ A,
                                                 const float* __restrict__ Bv,
                                                 const int* __restrict__ idx,
                                                 float* __restrict__ maxh,
                                                 float* __restrict__ minh,
                                                 float* __restrict__ gsum,
                                                 float* __restrict__ gsumsq) {
  constexpr int TPP = COUT / 4;
  constexpr int P = 256 / TPP;
  constexpr int PTS = 16;
  __shared__ float red[8][256];
  int tid = threadIdx.x;
  int p = tid / TPP, cq = tid % TPP;
  int b = blockIdx.x & 7, chunk = blockIdx.x >> 3;
  int nbase = b * Nn + chunk * PTS;
  const float4* A4 = (const float4*)A;
  const float4* B4 = (const float4*)Bv;
  float4 ts = make_float4(0, 0, 0, 0), ts2 = make_float4(0, 0, 0, 0);
  for (int it = 0; it < PTS / P; ++it) {
    int n = nbase + it * P + p;
    float4 a  = A4[(size_t)n * TPP + cq];
    float4 bc = B4[(size_t)n * TPP + cq];
    float4 base = make_float4(a.x - bc.x, a.y - bc.y, a.z - bc.z, a.w - bc.w);
    float4 mx = make_float4(-INFINITY, -INFINITY, -INFINITY, -INFINITY);
    float4 mn = make_float4(INFINITY, INFINITY, INFINITY, INFINITY);
    int gb = b * Nn;
    const int* ip = idx + (size_t)n * KNB;
    for (int k = 0; k < KNB; ++k) {
      int m = ip[k];
      float4 bn = B4[(size_t)(gb + m) * TPP + cq];
      float4 h = make_float4(base.x + bn.x, base.y + bn.y, base.z + bn.z, base.w + bn.w);
      mx.x = fmaxf(mx.x, h.x); mx.y = fmaxf(mx.y, h.y);
      mx.z = fmaxf(mx.z, h.z); mx.w = fmaxf(mx.w, h.w);
      mn.x = fminf(mn.x, h.x); mn.y = fminf(mn.y, h.y);
      mn.z = fminf(mn.z, h.z); mn.w = fminf(mn.w, h.w);
      ts.x += h.x; ts.y += h.y; ts.z += h.z; ts.w += h.w;
      ts2.x += h.x * h.x; ts2.y += h.y * h.y; ts2.z += h.z * h.z; ts2.w += h.w * h.w;
    }
    ((float4*)maxh)[(size_t)n * TPP + cq] = mx;
    ((float4*)minh)[(size_t)n * TPP + cq] = mn;
  }
  red[0][tid] = ts.x;  red[1][tid] = ts.y;  red[2][tid] = ts.z;  red[3][tid] = ts.w;
  red[4][tid] = ts2.x; red[5][tid] = ts2.y; red[6][tid] = ts2.z; red[7][tid] = ts2.w;
  __syncthreads();
  if (tid < COUT) {
    int q = tid & 3, g = tid >> 2;
    float s = 0.f, s2 = 0.f;
    for (int pp = 0; pp < P; ++pp) {
      int t2 = pp * TPP + g;
      s += red[q][t2]; s2 += red[4 + q][t2];
    }
    atomicAdd(&gsum[tid], s);
    atomicAdd(&gsumsq[tid], s2);
  }
}

// ------------------------------------------------- BN scale/shift per channel
__global__ void stats_k(const float* __restrict__ gsum, const float* __restrict__ gsumsq,
                        const float* __restrict__ gamma, const float* __restrict__ beta,
                        float* __restrict__ sA, float* __restrict__ sB, int COUT) {
  int c = threadIdx.x;
  if (c < COUT) {
    const float cnt = (float)((size_t)Bb * Nn * KNB);
    float mean = gsum[c] / cnt;
    float var = gsumsq[c] / cnt - mean * mean;
    var = fmaxf(var, 0.f);
    float s = gamma[c] * rsqrtf(var + EPSBN);
    sA[c] = s;
    sB[c] = beta[c] - mean * s;
  }
}

// ------------------------------------------------- apply BN+ReLU (layers 1,2)
__global__ __launch_bounds__(256) void apply_k(const float* __restrict__ maxh,
                                               const float* __restrict__ minh,
                                               const float* __restrict__ sA,
                                               const float* __restrict__ sB,
                                               float* __restrict__ out, int COUT) {
  int i = blockIdx.x * 256 + threadIdx.x;
  if (i >= NPT * COUT) return;
  int c = i % COUT;
  float s = sA[c];
  float h = (s >= 0.f) ? maxh[i] : minh[i];
  out[i] = fmaxf(s * h + sB[c], 0.f);
}

// ------------------------------------------------- layer-3 fused BN+ReLU+pool
__global__ __launch_bounds__(256) void gmax3_k(const float* __restrict__ maxh,
                                               const float* __restrict__ minh,
                                               const float* __restrict__ sA,
                                               const float* __restrict__ sB,
                                               unsigned* __restrict__ pooled) {
  int b = blockIdx.y, chunk = blockIdx.x;
  int c = threadIdx.x;
  float s = sA[c], t = sB[c];
  const float* src = (s >= 0.f) ? maxh : minh;
  const float* fb = src + ((size_t)b * Nn + chunk * 32) * 256;
  float m = 0.f;
  #pragma unroll 8
  for (int r = 0; r < 32; ++r) m = fmaxf(m, fmaxf(s * fb[(size_t)r * 256 + c] + t, 0.f));
  atomicMax(&pooled[b * 256 + c], __float_as_uint(m));
}

// ------------------------------------------------- final linear 8x256 @ 256x256
__global__ void final_k(const float* __restrict__ pooled, const float* __restrict__ wo,
                        const float* __restrict__ bo, float* __restrict__ out) {
  int b = blockIdx.x, c = threadIdx.x;
  const float* pr = pooled + b * 256;
  const float* wr = wo + c * 256;
  float s = bo[c];
  for (int j = 0; j < 256; ++j) s += pr[j] * wr[j];
  out[b * 256 + c] = s;
}

// ------------------------------------------------- layer driver
template <int CIN, int COUT, bool LAST>
static void run_layer(const float* fin, const float* W, const float* bias,
                      const float* gamma, const float* beta, float* fout,
                      float* nd, bool big, float* Abuf, float* Bvbuf, int* idxb,
                      float* xx, float* maxh, float* minh, float* gsum,
                      float* sA, float* sB, unsigned* pooled, hipStream_t stream) {
  row_sumsq_k<<<(NPT + 255) / 256, 256, 0, stream>>>(fin, xx, CIN);
  if (big) {
    dist_k<<<dim3(NTRI * Bb), 256, 0, stream>>>(fin, xx, nd, CIN);
    topk_k<<<NPT, 256, 0, stream>>>(nd, idxb);
  } else {
    for (int b = 0; b < Bb; ++b) {
      dist_k<<<dim3(NTRI, 1, 1), 256, 0, stream>>>(
          fin + (size_t)b * Nn * CIN, xx + (size_t)b * Nn, nd, CIN);
      topk_k<<<Nn, 256, 0, stream>>>(nd, idxb + (size_t)b * Nn * KNB);
    }
  }
  gemmAB_k<<<dim3(2 * COUT / 128, NPT / 128), 256, 0, stream>>>(fin, W, bias,
                                                                Abuf, Bvbuf, COUT, CIN);
  hipMemsetAsync(gsum, 0, 2 * 256 * sizeof(float), stream);
  combine_k<COUT><<<NPT / 16, 256, 0, stream>>>(Abuf, Bvbuf, idxb, maxh, minh,
                                                gsum, gsum + 256);
  stats_k<<<1, 256, 0, stream>>>(gsum, gsum + 256, gamma, beta, sA, sB, COUT);
  if (LAST) {
    gmax3_k<<<dim3(Nn / 32, Bb), 256, 0, stream>>>(maxh, minh, sA, sB, pooled);
  } else {
    apply_k<<<(NPT * COUT + 255) / 256, 256, 0, stream>>>(maxh, minh, sA, sB, fout, COUT);
  }
}

extern "C" void kernel_launch(void* const* d_in, const int* in_sizes, int n_in,
                              void* d_out, int out_size, void* d_ws, size_t ws_size,
                              hipStream_t stream) {
  const float* x   = (const float*)d_in[0];
  const float* w1  = (const float*)d_in[1];
  const float* b1  = (const float*)d_in[2];
  const float* g1  = (const float*)d_in[3];
  const float* be1 = (const float*)d_in[4];
  const float* w2  = (const float*)d_in[5];
  const float* b2  = (const float*)d_in[6];
  const float* g2  = (const float*)d_in[7];
  const float* be2 = (const float*)d_in[8];
  const float* w3  = (const float*)d_in[9];
  const float* b3  = (const float*)d_in[10];
  const float* g3  = (const float*)d_in[11];
  const float* be3 = (const float*)d_in[12];
  const float* wo  = (const float*)d_in[13];
  const float* bo  = (const float*)d_in[14];
  float* out = (float*)d_out;

  char* ws = (char*)d_ws;
  size_t off = 0;
  auto grab = [&](size_t bytes) -> char* {
    char* p = ws + off;
    off = (off + bytes + 255) & ~(size_t)255;
    return p;
  };
  const size_t SLAB = (size_t)NPT * 256 * 4;          // 16.78 MB
  const size_t ND_ALL = (size_t)Bb * Nn * Nn * 4;     // 134.2 MB
  const size_t NEED_BIG = ND_ALL + ((size_t)NPT * KNB * 4) + ((size_t)NPT * 4) +
                          ((size_t)NPT * 64 * 4) + ((size_t)NPT * 128 * 4) +
                          (16 << 10) + 16 * 256;
  bool big = (ws_size >= NEED_BIG);

  float *nd, *Abuf, *Bvbuf, *maxh, *minh;
  if (big) {
    nd    = (float*)grab(ND_ALL);
    Abuf  = nd;
    Bvbuf = (float*)((char*)nd + SLAB);
    maxh  = (float*)((char*)nd + 2 * SLAB);
    minh  = (float*)((char*)nd + 3 * SLAB);
  } else {
    nd    = (float*)grab((size_t)Nn * Nn * 4);
    Abuf  = nd;
    Bvbuf = (float*)grab(SLAB);
    maxh  = nullptr; minh = nullptr;
  }
  int*   idxb  = (int*)  grab((size_t)NPT * KNB * 4);
  float* xx    = (float*)grab((size_t)NPT * 4);
  float* feat1 = (float*)grab((size_t)NPT * 64 * 4);
  float* feat2 = (float*)grab((size_t)NPT * 128 * 4);
  if (!big) {
    maxh = (float*)grab(SLAB);
    minh = (float*)grab(SLAB);
  }
  float* gsum  = (float*)grab(2 * 256 * 4);
  float* sA    = (float*)grab(256 * 4);
  float* sB    = (float*)grab(256 * 4);
  unsigned* pooled = (unsigned*)grab(Bb * 256 * 4);

  hipMemsetAsync(pooled, 0, Bb * 256 * sizeof(unsigned), stream);

  run_layer<3, 64, false>(x, w1, b1, g1, be1, feat1, nd, big, Abuf, Bvbuf, idxb, xx,
                          maxh, minh, gsum, sA, sB, pooled, stream);
  run_layer<64, 128, false>(feat1, w2, b2, g2, be2, feat2, nd, big, Abuf, Bvbuf, idxb, xx,
                            maxh, minh, gsum, sA, sB, pooled, stream);
  run_layer<128, 256, true>(feat2, w3, b3, g3, be3, nullptr, nd, big, Abuf, Bvbuf, idxb, xx,
                            maxh, minh, gsum, sA, sB, pooled, stream);

  final_k<<<Bb, 256, 0, stream>>>((const float*)pooled, wo, bo, out);
  (void)in_sizes; (void)n_in; (void)out_size;
}

// Round 17
// 605.711 us; speedup vs baseline: 1.1409x; 1.1409x over previous
//
#include <hip/hip_runtime.h>
#include <cmath>

// DGCNN: B=8, N=2048, k=20, dims 3->64->128->256, fp32 throughout.
static constexpr int Bb  = 8;
static constexpr int Nn  = 2048;
static constexpr int KNB = 20;
static constexpr int NPT = Bb * Nn;
static constexpr int NTRI = 528;    // 32*33/2 triangular 64-tiles per batch
#define EPSBN 1e-5f

// LDS column swizzle for 128-wide staging (gemmAB).
__device__ __forceinline__ int permc(int c) { return c ^ (4 * (c >> 5)); }

// monotone uint key: order(key) == order(float); finite inputs -> key > 0
__device__ __forceinline__ unsigned mkkey(float v) {
  unsigned u = __float_as_uint(v);
  return (u & 0x80000000u) ? ~u : (u | 0x80000000u);
}

// ---------------------------------------------------------------- row |x|^2
__global__ __launch_bounds__(256) void row_sumsq_k(const float* __restrict__ f,
                                                   float* __restrict__ xx, int C) {
  int g = blockIdx.x * 256 + threadIdx.x;
  if (g >= NPT) return;
  const float* r = f + (size_t)g * C;
  float s = 0.f;
  for (int j = 0; j < C; ++j) { float v = r[j]; s += v * v; }
  xx[g] = s;
}

// ------------------------------------------------- neg_dist, symmetric 64x64
// nd[n][m] = 2*x_n.x_m - |x_n|^2 - |x_m|^2 ; diag forced to exactly 0.
// R15 config (best known): 64x64 tiles, 4x4 acc, 528 tri-tiles/batch, FULL
// mirror write (R16 showed triangle-only wrecks topk's coalescing: -80 us).
// R17: mirror transpose in ONE phase via 64x68 Sc (unioned over dead As/Bs,
// 17.4 KB) — was 4 phases x 2 barriers. XCD swizzle: batch = blockIdx.x & 7.
// HARD-LEARNED (R6/R7): no launch_bounds min-waves (spill); no runtime-
// indexed register arrays (scratch demotion). (R9/R10): no serial single-
// lane LDS selection / divergent long loops. (R12/R14): distinct b128 wave
// accesses are full-BW floor, not conflicts. (R16): nd reads must stay
// row-contiguous — don't trade write volume for read coalescing.
__global__ __launch_bounds__(256) void dist_k(const float* __restrict__ f,
                                              const float* __restrict__ xx,
                                              float* __restrict__ nd, int C) {
  __shared__ float lds[64 * 68];    // 17.4 KB unioned
  float* As = lds;                  // [k][row] rows 0..15 of k
  float* Bs = lds + 16 * 68;        // [k][col]
  float* Sc = lds;                  // transpose buf 64x68 (As/Bs dead)
  int tid = threadIdx.x, tx = tid & 15, ty = tid >> 4;
  int b, p;
  if (gridDim.x == NTRI * Bb) { b = blockIdx.x & 7; p = blockIdx.x >> 3; }
  else                        { b = blockIdx.z;     p = blockIdx.x; }
  const float* fb  = f  + (size_t)b * Nn * C;
  const float* xxb = xx + (size_t)b * Nn;
  float* ndb = nd + (size_t)b * Nn * Nn;
  // triangular decode: p in [0,528) -> (rblk, cblk), rblk <= cblk
  int rblk = 0;
  while (p >= 32 - rblk) { p -= 32 - rblk; ++rblk; }
  int rb = rblk * 64, cb = (rblk + p) * 64;
  bool diag = (rb == cb);
  int kk0 = tid & 15, rr = tid >> 4;
  float acc[4][4] = {};
  float pa[4], pb[4];
  {
    bool ok = kk0 < C;
    #pragma unroll
    for (int t = 0; t < 4; ++t) {
      int r2 = rr + 16 * t;
      pa[t] = ok ? fb[(size_t)(rb + r2) * C + kk0] : 0.f;
      pb[t] = ok ? fb[(size_t)(cb + r2) * C + kk0] : 0.f;
    }
  }
  for (int k0 = 0; k0 < C; k0 += 16) {
    __syncthreads();
    #pragma unroll
    for (int t = 0; t < 4; ++t) {
      int r2 = rr + 16 * t;
      As[kk0 * 68 + r2] = pa[t];
      Bs[kk0 * 68 + r2] = pb[t];
    }
    __syncthreads();
    if (k0 + 16 < C) {
      int k2 = k0 + 16 + kk0;
      bool ok2 = k2 < C;
      #pragma unroll
      for (int t = 0; t < 4; ++t) {
        int r2 = rr + 16 * t;
        pa[t] = ok2 ? fb[(size_t)(rb + r2) * C + k2] : 0.f;
        pb[t] = ok2 ? fb[(size_t)(cb + r2) * C + k2] : 0.f;
      }
    }
    #pragma unroll
    for (int kk = 0; kk < 16; ++kk) {
      float4 a4 = *(const float4*)&As[kk * 68 + 4 * ty];   // 4-addr broadcast
      float4 b4 = *(const float4*)&Bs[kk * 68 + 4 * tx];   // 16 distinct
      float av[4] = {a4.x, a4.y, a4.z, a4.w};
      float bv[4] = {b4.x, b4.y, b4.z, b4.w};
      #pragma unroll
      for (int i = 0; i < 4; ++i)
        #pragma unroll
        for (int j = 0; j < 4; ++j) acc[i][j] += av[i] * bv[j];
    }
  }
  // epilogue: finalize, store tile (+ mirrored tile if off-diag)
  float xr[4], xc[4];
  #pragma unroll
  for (int i = 0; i < 4; ++i) xr[i] = xxb[rb + 4 * ty + i];
  #pragma unroll
  for (int j = 0; j < 4; ++j) xc[j] = xxb[cb + 4 * tx + j];
  #pragma unroll
  for (int i = 0; i < 4; ++i) {
    int grow = rb + 4 * ty + i;
    #pragma unroll
    for (int j = 0; j < 4; ++j) {
      int gcol = cb + 4 * tx + j;
      float v = 2.f * acc[i][j] - xr[i] - xc[j];
      acc[i][j] = (grow == gcol) ? 0.f : v;
    }
    *(float4*)&ndb[(size_t)grow * Nn + cb + 4 * tx] =
        make_float4(acc[i][0], acc[i][1], acc[i][2], acc[i][3]);
  }
  if (!diag) {
    __syncthreads();   // As/Bs dead; Sc takes the whole buffer
    #pragma unroll
    for (int j = 0; j < 4; ++j)
      *(float4*)&Sc[(4 * tx + j) * 68 + 4 * ty] =
          make_float4(acc[0][j], acc[1][j], acc[2][j], acc[3][j]);
    __syncthreads();
    int srow = tid >> 2, q = tid & 3;   // 64 rows x 4 chunks of 16
    #pragma unroll
    for (int u = 0; u < 4; ++u) {
      float4 v = *(const float4*)&Sc[srow * 68 + 16 * q + 4 * u];
      *(float4*)&ndb[(size_t)(cb + srow) * Nn + rb + 16 * q + 4 * u] = v;
    }
  }
}

// ------------------------------------------------- top-20: threshold select
// One block per row (full-mirror nd, row-contiguous reads). (1) 8 keys/
// thread in REGISTERS, per-thread max; (2) each wave extracts the 5th-
// largest of its 64 maxima (shuffle-only); (3) T = min over 4 waves =>
// >=20 values >= T in the row => true top-20 + boundary ties are in
// {key >= T}; (4) append candidates (typ. 40-80, worst case 2048 = buffer
// size, still exact); (5) parallel rank-count extraction (R14).
__global__ __launch_bounds__(256) void topk_k(const float* __restrict__ nd,
                                              int* __restrict__ outidx) {
  __shared__ unsigned ck[Nn];
  __shared__ unsigned short ci[Nn];
  __shared__ unsigned Tw[4];
  __shared__ int s_cnt;
  int tid = threadIdx.x, lane = tid & 63;
  int n;
  if (gridDim.x == NPT) {            // XCD swizzle matches dist_k's writes
    int bb = blockIdx.x & 7, row = blockIdx.x >> 3;
    n = bb * Nn + row;
  } else {
    n = blockIdx.x;
  }
  const float4* rowp = (const float4*)(nd + (size_t)n * Nn);
  int* orow = outidx + (size_t)n * KNB;
  if (tid == 0) s_cnt = 0;
  float4 va = rowp[tid];
  float4 vb = rowp[tid + 256];
  unsigned k0 = mkkey(va.x), k1 = mkkey(va.y), k2 = mkkey(va.z), k3 = mkkey(va.w);
  unsigned k4 = mkkey(vb.x), k5 = mkkey(vb.y), k6 = mkkey(vb.z), k7 = mkkey(vb.w);
  unsigned t1 = k0;
  t1 = k1 > t1 ? k1 : t1; t1 = k2 > t1 ? k2 : t1; t1 = k3 > t1 ? k3 : t1;
  t1 = k4 > t1 ? k4 : t1; t1 = k5 > t1 ? k5 : t1; t1 = k6 > t1 ? k6 : t1;
  t1 = k7 > t1 ? k7 : t1;
  bool alive = true;
  unsigned wmax = 0;
  #pragma unroll
  for (int r = 0; r < 5; ++r) {
    unsigned v = alive ? t1 : 0u;
    wmax = v;
    #pragma unroll
    for (int off = 1; off < 64; off <<= 1) {
      unsigned o = (unsigned)__shfl_xor((int)wmax, off, 64);
      wmax = o > wmax ? o : wmax;
    }
    unsigned long long ball = __ballot(alive && t1 == wmax);
    int first = __ffsll((long long)ball) - 1;
    if (lane == first) alive = false;
  }
  if (lane == 0) Tw[tid >> 6] = wmax;
  __syncthreads();
  unsigned T = Tw[0];
  T = Tw[1] < T ? Tw[1] : T;
  T = Tw[2] < T ? Tw[2] : T;
  T = Tw[3] < T ? Tw[3] : T;
  int c0 = 4 * tid, c4 = 1024 + 4 * tid;
  if (k0 >= T) { int p2 = atomicAdd(&s_cnt, 1); ck[p2] = k0; ci[p2] = (unsigned short)(c0); }
  if (k1 >= T) { int p2 = atomicAdd(&s_cnt, 1); ck[p2] = k1; ci[p2] = (unsigned short)(c0 + 1); }
  if (k2 >= T) { int p2 = atomicAdd(&s_cnt, 1); ck[p2] = k2; ci[p2] = (unsigned short)(c0 + 2); }
  if (k3 >= T) { int p2 = atomicAdd(&s_cnt, 1); ck[p2] = k3; ci[p2] = (unsigned short)(c0 + 3); }
  if (k4 >= T) { int p2 = atomicAdd(&s_cnt, 1); ck[p2] = k4; ci[p2] = (unsigned short)(c4); }
  if (k5 >= T) { int p2 = atomicAdd(&s_cnt, 1); ck[p2] = k5; ci[p2] = (unsigned short)(c4 + 1); }
  if (k6 >= T) { int p2 = atomicAdd(&s_cnt, 1); ck[p2] = k6; ci[p2] = (unsigned short)(c4 + 2); }
  if (k7 >= T) { int p2 = atomicAdd(&s_cnt, 1); ck[p2] = k7; ci[p2] = (unsigned short)(c4 + 3); }
  __syncthreads();
  int nc = s_cnt;
  for (int j = tid; j < nc; j += 256) {
    unsigned kj = ck[j];
    unsigned ij = ci[j];
    int rank = 0;
    for (int i = 0; i < nc; ++i) {
      unsigned ki = ck[i];             // broadcast read
      unsigned ii = ci[i];
      rank += (ki > kj || (ki == kj && ii < ij)) ? 1 : 0;
    }
    if (rank < KNB) orow[rank] = (int)ij;
  }
}

// ------------------------------------------------- fused GEMM: A = X*W1^T + b, Bv = X*W2^T
__global__ __launch_bounds__(256) void gemmAB_k(const float* __restrict__ X,
                                                const float* __restrict__ W,
                                                const float* __restrict__ bias,
                                                float* __restrict__ A,
                                                float* __restrict__ Bv,
                                                int COUT, int CIN) {
  __shared__ float Xs[16][132];
  __shared__ float Ws[16][132];
  int tid = threadIdx.x, tx = tid & 15, ty = tid >> 4;
  int mb = blockIdx.y * 128, cb = blockIdx.x * 128;
  int kk0 = tid & 15, rr = tid >> 4;
  int ldw = 2 * CIN;
  float acc[8][8] = {};
  for (int k0 = 0; k0 < CIN; k0 += 16) {
    int k = k0 + kk0;
    bool ok = k < CIN;
    #pragma unroll
    for (int r2 = rr; r2 < 128; r2 += 16) {
      Xs[kk0][permc(r2)] = ok ? X[(size_t)(mb + r2) * CIN + k] : 0.f;
      int c2 = cb + r2;
      const float* wr = (c2 < COUT) ? (W + (size_t)c2 * ldw)
                                    : (W + (size_t)(c2 - COUT) * ldw + CIN);
      Ws[kk0][permc(r2)] = ok ? wr[k] : 0.f;
    }
    __syncthreads();
    #pragma unroll
    for (int kk = 0; kk < 16; ++kk) {
      float4 a0 = *(const float4*)&Xs[kk][permc(8 * ty)];
      float4 a1 = *(const float4*)&Xs[kk][permc(8 * ty + 4)];
      float4 b0 = *(const float4*)&Ws[kk][permc(8 * tx)];
      float4 b1 = *(const float4*)&Ws[kk][permc(8 * tx + 4)];
      float av[8] = {a0.x, a0.y, a0.z, a0.w, a1.x, a1.y, a1.z, a1.w};
      float bv[8] = {b0.x, b0.y, b0.z, b0.w, b1.x, b1.y, b1.z, b1.w};
      #pragma unroll
      for (int i = 0; i < 8; ++i)
        #pragma unroll
        for (int j = 0; j < 8; ++j) acc[i][j] += av[i] * bv[j];
    }
    __syncthreads();
  }
  int c0 = cb + 8 * tx;
  bool isA = (c0 < COUT);
  float bb[8] = {0, 0, 0, 0, 0, 0, 0, 0};
  if (isA) {
    float4 b4a = *(const float4*)&bias[c0];
    float4 b4b = *(const float4*)&bias[c0 + 4];
    bb[0] = b4a.x; bb[1] = b4a.y; bb[2] = b4a.z; bb[3] = b4a.w;
    bb[4] = b4b.x; bb[5] = b4b.y; bb[6] = b4b.z; bb[7] = b4b.w;
  }
  float* dst = isA ? A : Bv;
  int cc = isA ? c0 : (c0 - COUT);
  #pragma unroll
  for (int i = 0; i < 8; ++i) {
    int m = mb + 8 * ty + i;
    *(float4*)&dst[(size_t)m * COUT + cc] =
        make_float4(acc[i][0] + bb[0], acc[i][1] + bb[1], acc[i][2] + bb[2], acc[i][3] + bb[3]);
    *(float4*)&dst[(size_t)m * COUT + cc + 4] =
        make_float4(acc[i][4] + bb[4], acc[i][5] + bb[5], acc[i][6] + bb[6], acc[i][7] + bb[7]);
  }
}

// ------------------------------------------------- gather-combine + stats
// XCD-aware: batch = blockIdx.x % 8 so each XCD's L2 caches one batch's Bv slice.
template <int COUT>
__global__ __launch_bounds__(256) void combine_k(const float* __restrict__ A,
                                                 const float* __restrict__ Bv,
                                                 const int* __restrict__ idx,
                                                 float* __restrict__ maxh,
                                                 float* __restrict__ minh,
                                                 float* __restrict__ gsum,
                                                 float* __restrict__ gsumsq) {
  constexpr int TPP = COUT / 4;
  constexpr int P = 256 / TPP;
  constexpr int PTS = 16;
  __shared__ float red[8][256];
  int tid = threadIdx.x;
  int p = tid / TPP, cq = tid % TPP;
  int b = blockIdx.x & 7, chunk = blockIdx.x >> 3;
  int nbase = b * Nn + chunk * PTS;
  const float4* A4 = (const float4*)A;
  const float4* B4 = (const float4*)Bv;
  float4 ts = make_float4(0, 0, 0, 0), ts2 = make_float4(0, 0, 0, 0);
  for (int it = 0; it < PTS / P; ++it) {
    int n = nbase + it * P + p;
    float4 a  = A4[(size_t)n * TPP + cq];
    float4 bc = B4[(size_t)n * TPP + cq];
    float4 base = make_float4(a.x - bc.x, a.y - bc.y, a.z - bc.z, a.w - bc.w);
    float4 mx = make_float4(-INFINITY, -INFINITY, -INFINITY, -INFINITY);
    float4 mn = make_float4(INFINITY, INFINITY, INFINITY, INFINITY);
    int gb = b * Nn;
    const int* ip = idx + (size_t)n * KNB;
    for (int k = 0; k < KNB; ++k) {
      int m = ip[k];
      float4 bn = B4[(size_t)(gb + m) * TPP + cq];
      float4 h = make_float4(base.x + bn.x, base.y + bn.y, base.z + bn.z, base.w + bn.w);
      mx.x = fmaxf(mx.x, h.x); mx.y = fmaxf(mx.y, h.y);
      mx.z = fmaxf(mx.z, h.z); mx.w = fmaxf(mx.w, h.w);
      mn.x = fminf(mn.x, h.x); mn.y = fminf(mn.y, h.y);
      mn.z = fminf(mn.z, h.z); mn.w = fminf(mn.w, h.w);
      ts.x += h.x; ts.y += h.y; ts.z += h.z; ts.w += h.w;
      ts2.x += h.x * h.x; ts2.y += h.y * h.y; ts2.z += h.z * h.z; ts2.w += h.w * h.w;
    }
    ((float4*)maxh)[(size_t)n * TPP + cq] = mx;
    ((float4*)minh)[(size_t)n * TPP + cq] = mn;
  }
  red[0][tid] = ts.x;  red[1][tid] = ts.y;  red[2][tid] = ts.z;  red[3][tid] = ts.w;
  red[4][tid] = ts2.x; red[5][tid] = ts2.y; red[6][tid] = ts2.z; red[7][tid] = ts2.w;
  __syncthreads();
  if (tid < COUT) {
    int q = tid & 3, g = tid >> 2;
    float s = 0.f, s2 = 0.f;
    for (int pp = 0; pp < P; ++pp) {
      int t2 = pp * TPP + g;
      s += red[q][t2]; s2 += red[4 + q][t2];
    }
    atomicAdd(&gsum[tid], s);
    atomicAdd(&gsumsq[tid], s2);
  }
}

// ------------------------------------------------- BN scale/shift per channel
__global__ void stats_k(const float* __restrict__ gsum, const float* __restrict__ gsumsq,
                        const float* __restrict__ gamma, const float* __restrict__ beta,
                        float* __restrict__ sA, float* __restrict__ sB, int COUT) {
  int c = threadIdx.x;
  if (c < COUT) {
    const float cnt = (float)((size_t)Bb * Nn * KNB);
    float mean = gsum[c] / cnt;
    float var = gsumsq[c] / cnt - mean * mean;
    var = fmaxf(var, 0.f);
    float s = gamma[c] * rsqrtf(var + EPSBN);
    sA[c] = s;
    sB[c] = beta[c] - mean * s;
  }
}

// ------------------------------------------------- apply BN+ReLU + fused |x|^2
// Layers 1,2: writes fout AND xx (next layer's row sum-of-squares) in one
// pass — wave-level shuffle reduce (COUT=64: one wave per row; COUT=128:
// two waves per row combined via tiny LDS). Deletes row_sumsq for L2/L3
// and a full re-read of feat (R17).
template <int COUT>
__global__ __launch_bounds__(256) void apply_k(const float* __restrict__ maxh,
                                               const float* __restrict__ minh,
                                               const float* __restrict__ sA,
                                               const float* __restrict__ sB,
                                               float* __restrict__ out,
                                               float* __restrict__ xx) {
  __shared__ float part[4];
  int tid = threadIdx.x;
  int i = blockIdx.x * 256 + tid;
  int c = i & (COUT - 1);
  float s = sA[c];
  float h = (s >= 0.f) ? maxh[i] : minh[i];
  float v = fmaxf(s * h + sB[c], 0.f);
  out[i] = v;
  float v2 = v * v;
  #pragma unroll
  for (int off = 1; off < 64; off <<= 1)
    v2 += __shfl_xor(v2, off, 64);
  if constexpr (COUT == 64) {
    if ((tid & 63) == 0) xx[i >> 6] = v2;
  } else {                       // COUT == 128: rows span 2 waves
    if ((tid & 63) == 0) part[tid >> 6] = v2;
    __syncthreads();
    if (tid == 0) {
      int row0 = (blockIdx.x * 256) >> 7;
      xx[row0]     = part[0] + part[1];
      xx[row0 + 1] = part[2] + part[3];
    }
  }
}

// ------------------------------------------------- layer-3 fused BN+ReLU+pool
__global__ __launch_bounds__(256) void gmax3_k(const float* __restrict__ maxh,
                                               const float* __restrict__ minh,
                                               const float* __restrict__ sA,
                                               const float* __restrict__ sB,
                                               unsigned* __restrict__ pooled) {
  int b = blockIdx.y, chunk = blockIdx.x;
  int c = threadIdx.x;
  float s = sA[c], t = sB[c];
  const float* src = (s >= 0.f) ? maxh : minh;
  const float* fb = src + ((size_t)b * Nn + chunk * 32) * 256;
  float m = 0.f;
  #pragma unroll 8
  for (int r = 0; r < 32; ++r) m = fmaxf(m, fmaxf(s * fb[(size_t)r * 256 + c] + t, 0.f));
  atomicMax(&pooled[b * 256 + c], __float_as_uint(m));
}

// ------------------------------------------------- final linear 8x256 @ 256x256
__global__ void final_k(const float* __restrict__ pooled, const float* __restrict__ wo,
                        const float* __restrict__ bo, float* __restrict__ out) {
  int b = blockIdx.x, c = threadIdx.x;
  const float* pr = pooled + b * 256;
  const float* wr = wo + c * 256;
  float s = bo[c];
  for (int j = 0; j < 256; ++j) s += pr[j] * wr[j];
  out[b * 256 + c] = s;
}

// ------------------------------------------------- layer driver
// xx for this layer must already be populated (layer 1: row_sumsq on x;
// layers 2,3: produced by the previous layer's fused apply_k).
template <int CIN, int COUT, bool LAST>
static void run_layer(const float* fin, const float* W, const float* bias,
                      const float* gamma, const float* beta, float* fout,
                      float* nd, bool big, float* Abuf, float* Bvbuf, int* idxb,
                      float* xx, float* maxh, float* minh, float* gsum,
                      float* sA, float* sB, unsigned* pooled, hipStream_t stream) {
  if (big) {
    dist_k<<<dim3(NTRI * Bb), 256, 0, stream>>>(fin, xx, nd, CIN);
    topk_k<<<NPT, 256, 0, stream>>>(nd, idxb);
  } else {
    for (int b = 0; b < Bb; ++b) {
      dist_k<<<dim3(NTRI, 1, 1), 256, 0, stream>>>(
          fin + (size_t)b * Nn * CIN, xx + (size_t)b * Nn, nd, CIN);
      topk_k<<<Nn, 256, 0, stream>>>(nd, idxb + (size_t)b * Nn * KNB);
    }
  }
  gemmAB_k<<<dim3(2 * COUT / 128, NPT / 128), 256, 0, stream>>>(fin, W, bias,
                                                                Abuf, Bvbuf, COUT, CIN);
  hipMemsetAsync(gsum, 0, 2 * 256 * sizeof(float), stream);
  combine_k<COUT><<<NPT / 16, 256, 0, stream>>>(Abuf, Bvbuf, idxb, maxh, minh,
                                                gsum, gsum + 256);
  stats_k<<<1, 256, 0, stream>>>(gsum, gsum + 256, gamma, beta, sA, sB, COUT);
  if (LAST) {
    gmax3_k<<<dim3(Nn / 32, Bb), 256, 0, stream>>>(maxh, minh, sA, sB, pooled);
  } else {
    apply_k<COUT><<<(NPT * COUT) / 256, 256, 0, stream>>>(maxh, minh, sA, sB,
                                                          fout, xx);
  }
}

extern "C" void kernel_launch(void* const* d_in, const int* in_sizes, int n_in,
                              void* d_out, int out_size, void* d_ws, size_t ws_size,
                              hipStream_t stream) {
  const float* x   = (const float*)d_in[0];
  const float* w1  = (const float*)d_in[1];
  const float* b1  = (const float*)d_in[2];
  const float* g1  = (const float*)d_in[3];
  const float* be1 = (const float*)d_in[4];
  const float* w2  = (const float*)d_in[5];
  const float* b2  = (const float*)d_in[6];
  const float* g2  = (const float*)d_in[7];
  const float* be2 = (const float*)d_in[8];
  const float* w3  = (const float*)d_in[9];
  const float* b3  = (const float*)d_in[10];
  const float* g3  = (const float*)d_in[11];
  const float* be3 = (const float*)d_in[12];
  const float* wo  = (const float*)d_in[13];
  const float* bo  = (const float*)d_in[14];
  float* out = (float*)d_out;

  char* ws = (char*)d_ws;
  size_t off = 0;
  auto grab = [&](size_t bytes) -> char* {
    char* p = ws + off;
    off = (off + bytes + 255) & ~(size_t)255;
    return p;
  };
  const size_t SLAB = (size_t)NPT * 256 * 4;          // 16.78 MB
  const size_t ND_ALL = (size_t)Bb * Nn * Nn * 4;     // 134.2 MB
  const size_t NEED_BIG = ND_ALL + ((size_t)NPT * KNB * 4) + ((size_t)NPT * 4) +
                          ((size_t)NPT * 64 * 4) + ((size_t)NPT * 128 * 4) +
                          (16 << 10) + 16 * 256;
  bool big = (ws_size >= NEED_BIG);

  float *nd, *Abuf, *Bvbuf, *maxh, *minh;
  if (big) {
    nd    = (float*)grab(ND_ALL);
    Abuf  = nd;
    Bvbuf = (float*)((char*)nd + SLAB);
    maxh  = (float*)((char*)nd + 2 * SLAB);
    minh  = (float*)((char*)nd + 3 * SLAB);
  } else {
    nd    = (float*)grab((size_t)Nn * Nn * 4);
    Abuf  = nd;
    Bvbuf = (float*)grab(SLAB);
    maxh  = nullptr; minh = nullptr;
  }
  int*   idxb  = (int*)  grab((size_t)NPT * KNB * 4);
  float* xx    = (float*)grab((size_t)NPT * 4);
  float* feat1 = (float*)grab((size_t)NPT * 64 * 4);
  float* feat2 = (float*)grab((size_t)NPT * 128 * 4);
  if (!big) {
    maxh = (float*)grab(SLAB);
    minh = (float*)grab(SLAB);
  }
  float* gsum  = (float*)grab(2 * 256 * 4);
  float* sA    = (float*)grab(256 * 4);
  float* sB    = (float*)grab(256 * 4);
  unsigned* pooled = (unsigned*)grab(Bb * 256 * 4);

  hipMemsetAsync(pooled, 0, Bb * 256 * sizeof(unsigned), stream);

  row_sumsq_k<<<(NPT + 255) / 256, 256, 0, stream>>>(x, xx, 3);
  run_layer<3, 64, false>(x, w1, b1, g1, be1, feat1, nd, big, Abuf, Bvbuf, idxb, xx,
                          maxh, minh, gsum, sA, sB, pooled, stream);
  run_layer<64, 128, false>(feat1, w2, b2, g2, be2, feat2, nd, big, Abuf, Bvbuf, idxb, xx,
                            maxh, minh, gsum, sA, sB, pooled, stream);
  run_layer<128, 256, true>(feat2, w3, b3, g3, be3, nullptr, nd, big, Abuf, Bvbuf, idxb, xx,
                            maxh, minh, gsum, sA, sB, pooled, stream);

  final_k<<<Bb, 256, 0, stream>>>((const float*)pooled, wo, bo, out);
  (void)in_sizes; (void)n_in; (void)out_size;
}